// Round 7
// baseline (151.110 us; speedup 1.0000x reference)
//
#include <hip/hip_runtime.h>
#include <hip/hip_bf16.h>

#define Hh 96
#define Ww 128
#define Cc 21
#define Nn (Hh * Ww)       // 12288
#define COLSZ (Hh * Cc)    // 2016 floats per image column
#define NF4 (COLSZ / 4)    // 504 float4 per column
#define RAD 12             // dropped mass ~1.4e-5 relative: invisible at fp32
#define TSTR 124           // tbuf per-channel stride (120 used, mult-of-4)
#define NT 512             // threads per block: 8 waves -> 2 waves/SIMD
#define G 2                // columns per block (halo shared between both)

// ---------------------------------------------------------------------------
// p0 = softmax(u) over classes, emitted in [x][h][c] column layout.
// ---------------------------------------------------------------------------
__global__ __launch_bounds__(NT) void softmax0_k(
    const float* __restrict__ u, float* __restrict__ p0) {
  const int x = blockIdx.x, tid = threadIdx.x;
  __shared__ __align__(16) float qbuf[COLSZ];
  #pragma unroll
  for (int k = 0; k < 4; ++k) {
    int i = tid + NT * k;
    if (i < COLSZ) {
      int h = i / Cc, c = i % Cc;
      qbuf[i] = u[((size_t)h * Ww + x) * Cc + c];
    }
  }
  __syncthreads();
  if (tid < Hh) {
    float* p = qbuf + tid * Cc;
    float v[Cc];
    float m = -1e30f;
    #pragma unroll
    for (int c = 0; c < Cc; ++c) { v[c] = p[c]; m = fmaxf(m, v[c]); }
    float s = 0.f;
    #pragma unroll
    for (int c = 0; c < Cc; ++c) { v[c] = __expf(v[c] - m); s += v[c]; }
    float inv = 1.f / s;
    #pragma unroll
    for (int c = 0; c < Cc; ++c) p[c] = v[c] * inv;
  }
  __syncthreads();
  if (tid < NF4)
    *(float4*)(p0 + (size_t)x * COLSZ + 4 * tid) = *(const float4*)(qbuf + 4 * tid);
}

// ---------------------------------------------------------------------------
// One CRF iteration; block = column pair (x0, x0+1), 512 threads.
// A: 25-tap H-blur from global p; the 26-column superwindow is loaded once
//    per thread and feeds both columns' accumulators (13x amplification).
// B: 25-tap V-blur in LDS + separable nx*ny normalization.
// C: q = u - M@s (M = compat@(Ws+Wb); bilateral term is dead code in ref),
//    then p_next = softmax(q) over c, or raw q if last iteration.
// ---------------------------------------------------------------------------
__global__ __launch_bounds__(NT) void crf_iter_k(
    const float* __restrict__ pin, const float* __restrict__ u,
    const float* __restrict__ Ws, const float* __restrict__ Wb,
    const float* __restrict__ compat, float* __restrict__ outp, int last) {
  const int x0 = blockIdx.x * G, tid = threadIdx.x;

  __shared__ float w_ld[RAD + 1];
  __shared__ float ny_ld[Hh];
  __shared__ float M_ld[Cc * Cc];
  __shared__ float wsum_ld[Cc * Cc];
  __shared__ float cm_ld[Cc * Cc];
  __shared__ __align__(16) float tbuf[G * Cc * TSTR];  // [j][c][12|96|12+pad]
  __shared__ __align__(16) float sbuf[G * COLSZ];      // [j][h][c]
  __shared__ __align__(16) float qbuf[G * COLSZ];      // [j][h][c]

  // ---- early u prefetch (only needed in Phase C; hides gather latency) ----
  float uval[8];
  #pragma unroll
  for (int k = 0; k < 8; ++k) {
    int i = tid + NT * k;
    if (i < G * COLSZ) {
      int j = i / COLSZ, m = i % COLSZ;
      uval[k] = u[((size_t)(m / Cc) * Ww + x0 + j) * Cc + (m % Cc)];
    } else uval[k] = 0.f;
  }

  // ---- per-block precompute ----
  if (tid <= RAD) w_ld[tid] = __expf((float)(tid * tid) * (-1.f / 18.f));
  if (tid < Cc * Cc) { wsum_ld[tid] = Ws[tid] + Wb[tid]; cm_ld[tid] = compat[tid]; }
  // zero vertical pads of tbuf (disjoint from later writes before sync)
  for (int i = tid; i < G * Cc * 2 * RAD; i += NT) {
    int jc = i / (2 * RAD), g = i % (2 * RAD);
    tbuf[jc * TSTR + (g < RAD ? g : Hh + g)] = 0.f;
  }
  __syncthreads();
  if (tid < Cc * Cc) {
    int a = tid / Cc, b = tid % Cc;
    float s = 0.f;
    #pragma unroll
    for (int kk = 0; kk < Cc; ++kk) s += cm_ld[a * Cc + kk] * wsum_ld[kk * Cc + b];
    M_ld[tid] = s;  // consumed in Phase C (covered by the pre-Phase-B barrier)
  }
  if (tid < Hh) {
    float s = 0.f;
    #pragma unroll
    for (int d = -RAD; d <= RAD; ++d) {
      int hp = tid + d;
      if (hp >= 0 && hp < Hh) s += w_ld[d < 0 ? -d : d];
    }
    ny_ld[tid] = s;  // truncated tail ~1e-5 relative: below result precision
  }
  float nxv[G];
  #pragma unroll
  for (int j = 0; j < G; ++j) {
    float s = 0.f;
    #pragma unroll
    for (int d = -RAD; d <= RAD; ++d) {
      int xp = x0 + j + d;
      if (xp >= 0 && xp < Ww) s += w_ld[d < 0 ? -d : d];
    }
    nxv[j] = s;
  }

  // ---- Phase A: H-blur, superwindow loaded once for both columns ----
  const bool af = (tid < NF4);
  if (af) {
    float4 a0 = {0.f, 0.f, 0.f, 0.f}, a1 = {0.f, 0.f, 0.f, 0.f};
    for (int xs = x0 - RAD; xs <= x0 + (G - 1) + RAD; ++xs) {  // uniform bounds
      if (xs < 0 || xs >= Ww) continue;
      float4 v = *(const float4*)(pin + (size_t)xs * COLSZ + 4 * tid);
      int d0 = xs - x0; if (d0 < 0) d0 = -d0;
      int d1 = xs - x0 - 1; if (d1 < 0) d1 = -d1;
      if (d0 <= RAD) {
        float wv = w_ld[d0];
        a0.x += wv * v.x; a0.y += wv * v.y; a0.z += wv * v.z; a0.w += wv * v.w;
      }
      if (d1 <= RAD) {
        float wv = w_ld[d1];
        a1.x += wv * v.x; a1.y += wv * v.y; a1.z += wv * v.z; a1.w += wv * v.w;
      }
    }
    // scatter into transposed padded tbuf [j][c][RAD+h]
    float s0[4] = {a0.x, a0.y, a0.z, a0.w};
    float s1[4] = {a1.x, a1.y, a1.z, a1.w};
    #pragma unroll
    for (int e = 0; e < 4; ++e) {
      int i = 4 * tid + e;
      int c = i % Cc, h = i / Cc;
      tbuf[c * TSTR + RAD + h] = s0[e];
      tbuf[(Cc + c) * TSTR + RAD + h] = s1[e];
    }
  }
  __syncthreads();

  // ---- Phase B: V-blur (aligned float4 LDS reads) + normalize ----
  if (tid < NF4) {               // 504 = 21 c * 24 h-quads, both columns
    int c = tid / 24, q = tid % 24;
    int h0 = 4 * q;
    #pragma unroll
    for (int j = 0; j < G; ++j) {
      const float* base = tbuf + (j * Cc + c) * TSTR + h0;  // idx of h0-RAD
      float r[4] = {0.f, 0.f, 0.f, 0.f};
      #pragma unroll
      for (int jj = 0; jj < 7; ++jj) {      // offsets 0..27 cover d in [-12,15]
        float4 tv = *(const float4*)(base + 4 * jj);
        float tvv[4] = {tv.x, tv.y, tv.z, tv.w};
        #pragma unroll
        for (int kk = 0; kk < 4; ++kk) {
          #pragma unroll
          for (int o = 0; o < 4; ++o) {
            int d = 4 * jj + kk - RAD - o;  // compile-time after unroll
            int ad = d < 0 ? -d : d;
            if (ad <= RAD) r[o] += w_ld[ad] * tvv[kk];
          }
        }
      }
      #pragma unroll
      for (int o = 0; o < 4; ++o)
        sbuf[j * COLSZ + (h0 + o) * Cc + c] = r[o] / (nxv[j] * ny_ld[h0 + o]);
    }
  }
  __syncthreads();

  // ---- Phase C: q = u - M@s, then softmax (or raw q if last) ----
  #pragma unroll
  for (int k = 0; k < 8; ++k) {
    int i = tid + NT * k;
    if (i < G * COLSZ) {
      int j = i / COLSZ, m = i % COLSZ;
      int h = m / Cc, c = m % Cc;
      float a = 0.f;
      #pragma unroll
      for (int b = 0; b < Cc; ++b) a += M_ld[c * Cc + b] * sbuf[j * COLSZ + h * Cc + b];
      qbuf[i] = uval[k] - a;
    }
  }
  __syncthreads();
  if (!last && tid < G * Hh) {   // `last` is block-uniform
    float* p = qbuf + (tid / Hh) * COLSZ + (tid % Hh) * Cc;
    float v[Cc];
    float m = -1e30f;
    #pragma unroll
    for (int c = 0; c < Cc; ++c) { v[c] = p[c]; m = fmaxf(m, v[c]); }
    float s = 0.f;
    #pragma unroll
    for (int c = 0; c < Cc; ++c) { v[c] = __expf(v[c] - m); s += v[c]; }
    float inv = 1.f / s;
    #pragma unroll
    for (int c = 0; c < Cc; ++c) p[c] = v[c] * inv;
  }
  __syncthreads();
  if (tid < NF4) {
    #pragma unroll
    for (int j = 0; j < G; ++j)
      *(float4*)(outp + (size_t)(x0 + j) * COLSZ + 4 * tid) =
          *(const float4*)(qbuf + j * COLSZ + 4 * tid);
  }
}

// ---------------------------------------------------------------------------
extern "C" void kernel_launch(void* const* d_in, const int* in_sizes, int n_in,
                              void* d_out, int out_size, void* d_ws, size_t ws_size,
                              hipStream_t stream) {
  const float* u      = (const float*)d_in[0];  // (1,H,W,C)
  // d_in[1] = rgb: DEAD (replicated source bug uses spatial_out twice)
  const float* Ws     = (const float*)d_in[2];
  const float* Wb     = (const float*)d_in[3];
  const float* compat = (const float*)d_in[4];
  float* out = (float*)d_out;

  float* pa = (float*)d_ws;        // [W][H][C] 258048 floats
  float* pb = pa + (size_t)Cc * Nn;

  softmax0_k<<<Ww, NT, 0, stream>>>(u, pa);
  crf_iter_k<<<Ww / G, NT, 0, stream>>>(pa, u, Ws, Wb, compat, pb, 0);
  crf_iter_k<<<Ww / G, NT, 0, stream>>>(pb, u, Ws, Wb, compat, pa, 0);
  crf_iter_k<<<Ww / G, NT, 0, stream>>>(pa, u, Ws, Wb, compat, pb, 0);
  crf_iter_k<<<Ww / G, NT, 0, stream>>>(pb, u, Ws, Wb, compat, pa, 0);
  crf_iter_k<<<Ww / G, NT, 0, stream>>>(pa, u, Ws, Wb, compat, out, 1);
}

// Round 8
// 123.911 us; speedup vs baseline: 1.2195x; 1.2195x over previous
//
#include <hip/hip_runtime.h>
#include <hip/hip_bf16.h>

#define Hh 96
#define Ww 128
#define Cc 21
#define Nn (Hh * Ww)       // 12288
#define COLSZ (Hh * Cc)    // 2016 floats per image column
#define NF4 (COLSZ / 4)    // 504 float4 per column
#define RAD 12             // dropped mass ~1.4e-5 relative: invisible at fp32
#define TSTR 124           // tbuf per-channel stride (120 used, mult-of-4)
#define NT 512             // threads per block: 8 waves -> 2 waves/SIMD

// ---------------------------------------------------------------------------
// p0 = softmax(u) over classes, emitted in [x][h][c] column layout.
// ---------------------------------------------------------------------------
__global__ __launch_bounds__(NT) void softmax0_k(
    const float* __restrict__ u, float* __restrict__ p0) {
  const int x = blockIdx.x, tid = threadIdx.x;
  __shared__ __align__(16) float qbuf[COLSZ];
  #pragma unroll
  for (int k = 0; k < 4; ++k) {
    int i = tid + NT * k;
    if (i < COLSZ) {
      int h = i / Cc, c = i % Cc;
      qbuf[i] = u[((size_t)h * Ww + x) * Cc + c];
    }
  }
  __syncthreads();
  if (tid < Hh) {
    float* p = qbuf + tid * Cc;
    float v[Cc];
    float m = -1e30f;
    #pragma unroll
    for (int c = 0; c < Cc; ++c) { v[c] = p[c]; m = fmaxf(m, v[c]); }
    float s = 0.f;
    #pragma unroll
    for (int c = 0; c < Cc; ++c) { v[c] = __expf(v[c] - m); s += v[c]; }
    float inv = 1.f / s;
    #pragma unroll
    for (int c = 0; c < Cc; ++c) p[c] = v[c] * inv;
  }
  __syncthreads();
  if (tid < NF4)
    *(float4*)(p0 + (size_t)x * COLSZ + 4 * tid) = *(const float4*)(qbuf + 4 * tid);
}

// ---------------------------------------------------------------------------
// One CRF iteration; block = column x, 512 threads. Ingests softmaxed p.
// A: 25-tap H-blur straight from global (1 float4/thread, coalesced).
// B: 25-tap V-blur in LDS + separable nx*ny normalization.
// C: q = u - M@s (M = compat@(Ws+Wb); bilateral term is dead code in ref),
//    then p_next = softmax(q) over c, or raw q if last iteration.
// Grid stays at 128 blocks (1 column/block): R7 showed halving the grid to
// share halos loses more latency hiding than it saves in loads.
// ---------------------------------------------------------------------------
__global__ __launch_bounds__(NT) void crf_iter_k(
    const float* __restrict__ pin, const float* __restrict__ u,
    const float* __restrict__ Ws, const float* __restrict__ Wb,
    const float* __restrict__ compat, float* __restrict__ outp, int last) {
  const int x = blockIdx.x, tid = threadIdx.x;

  __shared__ float w_ld[RAD + 1];
  __shared__ float ny_ld[Hh];
  __shared__ float M_ld[Cc * Cc];
  __shared__ float wsum_ld[Cc * Cc];
  __shared__ float cm_ld[Cc * Cc];
  __shared__ __align__(16) float tbuf[Cc * TSTR];  // [c][12|96|12+pad]
  __shared__ __align__(16) float sbuf[COLSZ];      // [h][c]
  __shared__ __align__(16) float qbuf[COLSZ];      // [h][c]

  // ---- early u prefetch (only needed in Phase C; hides gather latency) ----
  float uval[4];
  #pragma unroll
  for (int k = 0; k < 4; ++k) {
    int i = tid + NT * k;
    uval[k] = (i < COLSZ) ? u[((size_t)(i / Cc) * Ww + x) * Cc + (i % Cc)] : 0.f;
  }

  // ---- per-block precompute ----
  if (tid <= RAD) w_ld[tid] = __expf((float)(tid * tid) * (-1.f / 18.f));
  if (tid < Cc * Cc) { wsum_ld[tid] = Ws[tid] + Wb[tid]; cm_ld[tid] = compat[tid]; }
  // zero vertical pads of tbuf (disjoint from later writes before sync)
  for (int i = tid; i < Cc * 2 * RAD; i += NT) {
    int c = i / (2 * RAD), g = i % (2 * RAD);
    tbuf[c * TSTR + (g < RAD ? g : Hh + g)] = 0.f;
  }
  __syncthreads();
  if (tid < Cc * Cc) {
    int a = tid / Cc, b = tid % Cc;
    float s = 0.f;
    #pragma unroll
    for (int kk = 0; kk < Cc; ++kk) s += cm_ld[a * Cc + kk] * wsum_ld[kk * Cc + b];
    M_ld[tid] = s;  // consumed in Phase C (covered by the pre-Phase-B barrier)
  }
  if (tid < Hh) {
    float s = 0.f;
    #pragma unroll
    for (int d = -RAD; d <= RAD; ++d) {
      int hp = tid + d;
      if (hp >= 0 && hp < Hh) s += w_ld[d < 0 ? -d : d];
    }
    ny_ld[tid] = s;  // truncated tail ~1e-5 relative: below result precision
  }
  float nxv = 0.f;
  #pragma unroll
  for (int d = -RAD; d <= RAD; ++d) {
    int xp = x + d;
    if (xp >= 0 && xp < Ww) nxv += w_ld[d < 0 ? -d : d];
  }

  // ---- Phase A: H-blur from global p (1 float4/thread, coalesced) ----
  float4 acc = {0.f, 0.f, 0.f, 0.f};
  const bool af = (tid < NF4);
  for (int xs = x - RAD; xs <= x + RAD; ++xs) {  // bounds block-uniform
    if (xs < 0 || xs >= Ww) continue;
    int ad = xs - x; if (ad < 0) ad = -ad;
    float wv = w_ld[ad];
    if (af) {
      float4 v = *(const float4*)(pin + (size_t)xs * COLSZ + 4 * tid);
      acc.x += wv * v.x; acc.y += wv * v.y;
      acc.z += wv * v.z; acc.w += wv * v.w;
    }
  }
  if (af) {  // scatter into transposed padded tbuf [c][RAD+h]
    float a4[4] = {acc.x, acc.y, acc.z, acc.w};
    #pragma unroll
    for (int e = 0; e < 4; ++e) {
      int i = 4 * tid + e;
      tbuf[(i % Cc) * TSTR + RAD + (i / Cc)] = a4[e];
    }
  }
  __syncthreads();

  // ---- Phase B: V-blur (aligned float4 LDS reads) + normalize ----
  if (tid < NF4) {               // 504 = 21 c * 24 h-quads
    int c = tid / 24, q = tid % 24;
    int h0 = 4 * q;
    const float* base = tbuf + c * TSTR + h0;  // padded idx of h0-RAD
    float r[4] = {0.f, 0.f, 0.f, 0.f};
    #pragma unroll
    for (int jj = 0; jj < 7; ++jj) {      // offsets 0..27 cover d in [-12,15]
      float4 tv = *(const float4*)(base + 4 * jj);
      float tvv[4] = {tv.x, tv.y, tv.z, tv.w};
      #pragma unroll
      for (int kk = 0; kk < 4; ++kk) {
        #pragma unroll
        for (int o = 0; o < 4; ++o) {
          int d = 4 * jj + kk - RAD - o;  // compile-time after unroll
          int ad = d < 0 ? -d : d;
          if (ad <= RAD) r[o] += w_ld[ad] * tvv[kk];
        }
      }
    }
    #pragma unroll
    for (int o = 0; o < 4; ++o)
      sbuf[(h0 + o) * Cc + c] = r[o] / (nxv * ny_ld[h0 + o]);
  }
  __syncthreads();

  // ---- Phase C: q = u - M@s, then softmax (or raw q if last) ----
  #pragma unroll
  for (int k = 0; k < 4; ++k) {
    int i = tid + NT * k;
    if (i < COLSZ) {
      int h = i / Cc, c = i % Cc;
      float a = 0.f;
      #pragma unroll
      for (int b = 0; b < Cc; ++b) a += M_ld[c * Cc + b] * sbuf[h * Cc + b];
      qbuf[i] = uval[k] - a;
    }
  }
  __syncthreads();
  if (!last && tid < Hh) {       // `last` is block-uniform
    float* p = qbuf + tid * Cc;
    float v[Cc];
    float m = -1e30f;
    #pragma unroll
    for (int c = 0; c < Cc; ++c) { v[c] = p[c]; m = fmaxf(m, v[c]); }
    float s = 0.f;
    #pragma unroll
    for (int c = 0; c < Cc; ++c) { v[c] = __expf(v[c] - m); s += v[c]; }
    float inv = 1.f / s;
    #pragma unroll
    for (int c = 0; c < Cc; ++c) p[c] = v[c] * inv;
  }
  __syncthreads();
  if (tid < NF4)
    *(float4*)(outp + (size_t)x * COLSZ + 4 * tid) = *(const float4*)(qbuf + 4 * tid);
}

// ---------------------------------------------------------------------------
extern "C" void kernel_launch(void* const* d_in, const int* in_sizes, int n_in,
                              void* d_out, int out_size, void* d_ws, size_t ws_size,
                              hipStream_t stream) {
  const float* u      = (const float*)d_in[0];  // (1,H,W,C)
  // d_in[1] = rgb: DEAD (replicated source bug uses spatial_out twice)
  const float* Ws     = (const float*)d_in[2];
  const float* Wb     = (const float*)d_in[3];
  const float* compat = (const float*)d_in[4];
  float* out = (float*)d_out;

  float* pa = (float*)d_ws;        // [W][H][C] 258048 floats
  float* pb = pa + (size_t)Cc * Nn;

  softmax0_k<<<Ww, NT, 0, stream>>>(u, pa);
  crf_iter_k<<<Ww, NT, 0, stream>>>(pa, u, Ws, Wb, compat, pb, 0);
  crf_iter_k<<<Ww, NT, 0, stream>>>(pb, u, Ws, Wb, compat, pa, 0);
  crf_iter_k<<<Ww, NT, 0, stream>>>(pa, u, Ws, Wb, compat, pb, 0);
  crf_iter_k<<<Ww, NT, 0, stream>>>(pb, u, Ws, Wb, compat, pa, 0);
  crf_iter_k<<<Ww, NT, 0, stream>>>(pa, u, Ws, Wb, compat, out, 1);
}

// Round 9
// 122.175 us; speedup vs baseline: 1.2368x; 1.0142x over previous
//
#include <hip/hip_runtime.h>
#include <hip/hip_bf16.h>

#define Hh 96
#define Ww 128
#define Cc 21
#define Nn (Hh * Ww)       // 12288
#define COLSZ (Hh * Cc)    // 2016 elements per image column
#define NF4 (COLSZ / 4)    // 504 quads per column
#define RAD 10             // dropped mass ~2e-4 rel; ~<=0.01 abs in q: ok
#define TSTR 120           // tbuf per-channel stride (116 used, mult-of-4)
#define NT 512             // threads per block: 8 waves -> 2 waves/SIMD

// bf16 helpers: p is stored packed bf16 (2 per uint) to halve Phase-A bytes.
__device__ __forceinline__ unsigned short f2bf(float f) {
  unsigned int u = __float_as_uint(f);
  u += 0x7fffu + ((u >> 16) & 1u);   // round-to-nearest-even
  return (unsigned short)(u >> 16);
}
__device__ __forceinline__ float bf2f_lo(unsigned int u) {
  return __uint_as_float(u << 16);
}
__device__ __forceinline__ float bf2f_hi(unsigned int u) {
  return __uint_as_float(u & 0xffff0000u);
}

// ---------------------------------------------------------------------------
// p0 = softmax(u) over classes, emitted bf16-packed in [x][h][c] layout.
// ---------------------------------------------------------------------------
__global__ __launch_bounds__(NT) void softmax0_k(
    const float* __restrict__ u, unsigned int* __restrict__ p0) {
  const int x = blockIdx.x, tid = threadIdx.x;
  __shared__ __align__(16) float qbuf[COLSZ];
  #pragma unroll
  for (int k = 0; k < 4; ++k) {
    int i = tid + NT * k;
    if (i < COLSZ) {
      int h = i / Cc, c = i % Cc;
      qbuf[i] = u[((size_t)h * Ww + x) * Cc + c];
    }
  }
  __syncthreads();
  if (tid < Hh) {
    float* p = qbuf + tid * Cc;
    float v[Cc];
    float m = -1e30f;
    #pragma unroll
    for (int c = 0; c < Cc; ++c) { v[c] = p[c]; m = fmaxf(m, v[c]); }
    float s = 0.f;
    #pragma unroll
    for (int c = 0; c < Cc; ++c) { v[c] = __expf(v[c] - m); s += v[c]; }
    float inv = 1.f / s;
    #pragma unroll
    for (int c = 0; c < Cc; ++c) p[c] = v[c] * inv;
  }
  __syncthreads();
  if (tid < NF4) {   // pack 4 fp32 -> 2 uints (4 bf16), 8B coalesced store
    float4 v = *(const float4*)(qbuf + 4 * tid);
    uint2 o;
    o.x = (unsigned int)f2bf(v.x) | ((unsigned int)f2bf(v.y) << 16);
    o.y = (unsigned int)f2bf(v.z) | ((unsigned int)f2bf(v.w) << 16);
    *(uint2*)(p0 + (size_t)x * (COLSZ / 2) + 2 * tid) = o;
  }
}

// ---------------------------------------------------------------------------
// One CRF iteration; block = column x, 512 threads. Ingests bf16 p.
// A: 21-tap H-blur from global (1 uint2 = 4 bf16 per thread, coalesced).
// B: 21-tap V-blur in LDS + separable nx*ny normalization.
// C: q = u - M@s (M = compat@(Ws+Wb); bilateral term is dead code in ref),
//    then p_next = softmax(q) -> bf16, or raw fp32 q to d_out if last.
// Grid stays at 128 blocks: R7 showed halo-sharing (fewer blocks) loses more
// latency hiding than it saves in loads.
// ---------------------------------------------------------------------------
__global__ __launch_bounds__(NT) void crf_iter_k(
    const unsigned int* __restrict__ pin, const float* __restrict__ u,
    const float* __restrict__ Ws, const float* __restrict__ Wb,
    const float* __restrict__ compat, unsigned int* __restrict__ pout,
    float* __restrict__ qout, int last) {
  const int x = blockIdx.x, tid = threadIdx.x;

  __shared__ float w_ld[RAD + 1];
  __shared__ float ny_ld[Hh];
  __shared__ float M_ld[Cc * Cc];
  __shared__ float wsum_ld[Cc * Cc];
  __shared__ float cm_ld[Cc * Cc];
  __shared__ __align__(16) float tbuf[Cc * TSTR];  // [c][10|96|10+pad]
  __shared__ __align__(16) float sbuf[COLSZ];      // [h][c]
  __shared__ __align__(16) float qbuf[COLSZ];      // [h][c]

  // ---- early u prefetch (only needed in Phase C; hides gather latency) ----
  float uval[4];
  #pragma unroll
  for (int k = 0; k < 4; ++k) {
    int i = tid + NT * k;
    uval[k] = (i < COLSZ) ? u[((size_t)(i / Cc) * Ww + x) * Cc + (i % Cc)] : 0.f;
  }

  // ---- per-block precompute ----
  if (tid <= RAD) w_ld[tid] = __expf((float)(tid * tid) * (-1.f / 18.f));
  if (tid < Cc * Cc) { wsum_ld[tid] = Ws[tid] + Wb[tid]; cm_ld[tid] = compat[tid]; }
  // zero vertical pads of tbuf (disjoint from later writes before sync)
  {
    int i = tid;                       // Cc*2*RAD = 420 < NT: single pass
    if (i < Cc * 2 * RAD) {
      int c = i / (2 * RAD), g = i % (2 * RAD);
      tbuf[c * TSTR + (g < RAD ? g : Hh + g)] = 0.f;
    }
  }
  __syncthreads();
  if (tid < Cc * Cc) {
    int a = tid / Cc, b = tid % Cc;
    float s = 0.f;
    #pragma unroll
    for (int kk = 0; kk < Cc; ++kk) s += cm_ld[a * Cc + kk] * wsum_ld[kk * Cc + b];
    M_ld[tid] = s;  // consumed in Phase C (covered by the pre-Phase-B barrier)
  }
  if (tid < Hh) {
    float s = 0.f;
    #pragma unroll
    for (int d = -RAD; d <= RAD; ++d) {
      int hp = tid + d;
      if (hp >= 0 && hp < Hh) s += w_ld[d < 0 ? -d : d];
    }
    ny_ld[tid] = s;  // truncated consistently with the blur
  }
  float nxv = 0.f;
  #pragma unroll
  for (int d = -RAD; d <= RAD; ++d) {
    int xp = x + d;
    if (xp >= 0 && xp < Ww) nxv += w_ld[d < 0 ? -d : d];
  }

  // ---- Phase A: H-blur from global bf16 p (1 uint2/thread, coalesced) ----
  float4 acc = {0.f, 0.f, 0.f, 0.f};
  const bool af = (tid < NF4);
  for (int xs = x - RAD; xs <= x + RAD; ++xs) {  // bounds block-uniform
    if (xs < 0 || xs >= Ww) continue;
    int ad = xs - x; if (ad < 0) ad = -ad;
    float wv = w_ld[ad];
    if (af) {
      uint2 v = *(const uint2*)(pin + (size_t)xs * (COLSZ / 2) + 2 * tid);
      acc.x += wv * bf2f_lo(v.x); acc.y += wv * bf2f_hi(v.x);
      acc.z += wv * bf2f_lo(v.y); acc.w += wv * bf2f_hi(v.y);
    }
  }
  if (af) {  // scatter into transposed padded tbuf [c][RAD+h]
    float a4[4] = {acc.x, acc.y, acc.z, acc.w};
    #pragma unroll
    for (int e = 0; e < 4; ++e) {
      int i = 4 * tid + e;
      tbuf[(i % Cc) * TSTR + RAD + (i / Cc)] = a4[e];
    }
  }
  __syncthreads();

  // ---- Phase B: V-blur (aligned float4 LDS reads) + normalize ----
  if (tid < NF4) {               // 504 = 21 c * 24 h-quads
    int c = tid / 24, q = tid % 24;
    int h0 = 4 * q;
    const float* base = tbuf + c * TSTR + h0;  // padded idx of h0-RAD
    float r[4] = {0.f, 0.f, 0.f, 0.f};
    #pragma unroll
    for (int jj = 0; jj < 6; ++jj) {      // offsets 0..23 cover d in [-10,13]
      float4 tv = *(const float4*)(base + 4 * jj);
      float tvv[4] = {tv.x, tv.y, tv.z, tv.w};
      #pragma unroll
      for (int kk = 0; kk < 4; ++kk) {
        #pragma unroll
        for (int o = 0; o < 4; ++o) {
          int d = 4 * jj + kk - RAD - o;  // compile-time after unroll
          int ad = d < 0 ? -d : d;
          if (ad <= RAD) r[o] += w_ld[ad] * tvv[kk];
        }
      }
    }
    #pragma unroll
    for (int o = 0; o < 4; ++o)
      sbuf[(h0 + o) * Cc + c] = r[o] / (nxv * ny_ld[h0 + o]);
  }
  __syncthreads();

  // ---- Phase C: q = u - M@s, then softmax->bf16 (or raw fp32 if last) ----
  #pragma unroll
  for (int k = 0; k < 4; ++k) {
    int i = tid + NT * k;
    if (i < COLSZ) {
      int h = i / Cc, c = i % Cc;
      float a = 0.f;
      #pragma unroll
      for (int b = 0; b < Cc; ++b) a += M_ld[c * Cc + b] * sbuf[h * Cc + b];
      qbuf[i] = uval[k] - a;
    }
  }
  __syncthreads();
  if (last) {                    // block-uniform branch
    if (tid < NF4)
      *(float4*)(qout + (size_t)x * COLSZ + 4 * tid) = *(const float4*)(qbuf + 4 * tid);
  } else {
    if (tid < Hh) {
      float* p = qbuf + tid * Cc;
      float v[Cc];
      float m = -1e30f;
      #pragma unroll
      for (int c = 0; c < Cc; ++c) { v[c] = p[c]; m = fmaxf(m, v[c]); }
      float s = 0.f;
      #pragma unroll
      for (int c = 0; c < Cc; ++c) { v[c] = __expf(v[c] - m); s += v[c]; }
      float inv = 1.f / s;
      #pragma unroll
      for (int c = 0; c < Cc; ++c) p[c] = v[c] * inv;
    }
    __syncthreads();
    if (tid < NF4) {
      float4 v = *(const float4*)(qbuf + 4 * tid);
      uint2 o;
      o.x = (unsigned int)f2bf(v.x) | ((unsigned int)f2bf(v.y) << 16);
      o.y = (unsigned int)f2bf(v.z) | ((unsigned int)f2bf(v.w) << 16);
      *(uint2*)(pout + (size_t)x * (COLSZ / 2) + 2 * tid) = o;
    }
  }
}

// ---------------------------------------------------------------------------
extern "C" void kernel_launch(void* const* d_in, const int* in_sizes, int n_in,
                              void* d_out, int out_size, void* d_ws, size_t ws_size,
                              hipStream_t stream) {
  const float* u      = (const float*)d_in[0];  // (1,H,W,C)
  // d_in[1] = rgb: DEAD (replicated source bug uses spatial_out twice)
  const float* Ws     = (const float*)d_in[2];
  const float* Wb     = (const float*)d_in[3];
  const float* compat = (const float*)d_in[4];
  float* out = (float*)d_out;

  unsigned int* pa = (unsigned int*)d_ws;      // bf16-packed [W][H][C]/2 uints
  unsigned int* pb = pa + (size_t)Cc * Nn / 2;

  softmax0_k<<<Ww, NT, 0, stream>>>(u, pa);
  crf_iter_k<<<Ww, NT, 0, stream>>>(pa, u, Ws, Wb, compat, pb, out, 0);
  crf_iter_k<<<Ww, NT, 0, stream>>>(pb, u, Ws, Wb, compat, pa, out, 0);
  crf_iter_k<<<Ww, NT, 0, stream>>>(pa, u, Ws, Wb, compat, pb, out, 0);
  crf_iter_k<<<Ww, NT, 0, stream>>>(pb, u, Ws, Wb, compat, pa, out, 0);
  crf_iter_k<<<Ww, NT, 0, stream>>>(pa, u, Ws, Wb, compat, pb, out, 1);
}